// Round 15
// baseline (205.175 us; speedup 1.0000x reference)
//
#include <hip/hip_runtime.h>
#include <hip/hip_bf16.h>
#include <hip/hip_cooperative_groups.h>

namespace cg = cooperative_groups;

typedef __attribute__((ext_vector_type(8))) short short8;
typedef __attribute__((ext_vector_type(4))) float floatx4;
typedef __attribute__((ext_vector_type(4))) float f32x4;
typedef __attribute__((ext_vector_type(16))) float f32x16;
typedef unsigned short u16;
typedef unsigned int u32;
typedef __attribute__((ext_vector_type(4))) unsigned int u32x4;
typedef __attribute__((ext_vector_type(8))) unsigned short ushort8;

#define LSEQ 1024
#define CHD  128
#define CEXP 0.12751744900425577f   // (1/sqrt(128)) * log2(e)
#define THR_RAW 62.73318f           // 8 / CEXP

static __device__ __forceinline__ float b2f(u16 u) {
  union { u32 i; float f; } x; x.i = ((u32)u) << 16; return x.f;
}
static __device__ __forceinline__ u32 cvtpk(float a, float b) {
  u32 r;
  asm("v_cvt_pk_bf16_f32 %0, %1, %2" : "=v"(r) : "v"(a), "v"(b));
  return r;
}
static __device__ __forceinline__ void swap32(u32& a, u32& b) {
  asm("v_permlane32_swap_b32 %0, %1" : "+v"(a), "+v"(b));
}
static __device__ __forceinline__ short8 mk8(u32 a, u32 b, u32 c, u32 d) {
  union { u32x4 u; short8 s; } x;
  x.u[0] = a; x.u[1] = b; x.u[2] = c; x.u[3] = d;
  return x.s;
}
static __device__ __forceinline__ float exp2f_fast(float x) {
  float r;
  asm("v_exp_f32 %0, %1" : "=v"(r) : "v"(x));
  return r;
}
static __device__ __forceinline__ void gl_lds16(const void* g, void* l) {
  __builtin_amdgcn_global_load_lds((__attribute__((address_space(1))) const void*)g,
                                   (__attribute__((address_space(3))) void*)l, 16, 0, 0);
}
#define BARRIER() do { asm volatile("" ::: "memory"); __builtin_amdgcn_s_barrier(); asm volatile("" ::: "memory"); } while (0)
#define LGKM0()   do { asm volatile("s_waitcnt lgkmcnt(0)" ::: "memory"); __builtin_amdgcn_sched_barrier(0); } while (0)

// ---- prep both inputs (z<64) + W convert (z=64,65) ----
__global__ __launch_bounds__(256) void k_prep(const float* __restrict__ cin,
                                              const float* __restrict__ ein,
                                              const float* __restrict__ Wf,
                                              u16* __restrict__ cV, u16* __restrict__ cT,
                                              u16* __restrict__ eV, u16* __restrict__ eT,
                                              u16* __restrict__ wb) {
  __shared__ u16 tile[32][72];
  int z = blockIdx.z;
  int tid = threadIdx.x;
  if (z >= 64) {
    int wblk = (z - 64) * 64 + blockIdx.y * 16 + blockIdx.x;
    int base = (wblk * 256 + tid) * 8;
    f32x4 a = *(const f32x4*)(Wf + base);
    f32x4 b = *(const f32x4*)(Wf + base + 4);
    u32x4 u;
    u[0] = cvtpk(a[0], a[1]); u[1] = cvtpk(a[2], a[3]);
    u[2] = cvtpk(b[0], b[1]); u[3] = cvtpk(b[2], b[3]);
    *(u32x4*)(wb + base) = u;
    return;
  }
  const float* in = (z < 32) ? cin : ein;
  u16* outV = (z < 32) ? cV : eV;
  u16* outT = (z < 32) ? cT : eT;
  int bh = z & 31, c0 = blockIdx.y * 32, s0 = blockIdx.x * 64;
  int cl = tid >> 3, sc = tid & 7;
  size_t off = ((size_t)bh * CHD + c0 + cl) * LSEQ + s0 + sc * 8;
  f32x4 a = *(const f32x4*)(in + off);
  f32x4 b = *(const f32x4*)(in + off + 4);
  u32x4 u;
  u[0] = cvtpk(a[0], a[1]); u[1] = cvtpk(a[2], a[3]);
  u[2] = cvtpk(b[0], b[1]); u[3] = cvtpk(b[2], b[3]);
  *(u32x4*)(outV + off) = u;
  *(u32x4*)&tile[cl][sc * 8] = u;
  __syncthreads();
  int sl = tid >> 2, cc = tid & 3;
  ushort8 v;
#pragma unroll
  for (int j = 0; j < 8; ++j) v[j] = tile[cc * 8 + j][sl];
  *(ushort8*)(outT + ((size_t)bh * LSEQ + s0 + sl) * CHD + c0 + cc * 8) = v;
}

// ---- fused double flash attention: 4 waves (2 tw x 2 sw), phased schedule (r11) ----
__global__ __launch_bounds__(256, 2) void k_attn(const u16* __restrict__ eT,
                                                 const u16* __restrict__ cT,
                                                 const u16* __restrict__ cV,
                                                 const u16* __restrict__ eV,
                                                 u16* __restrict__ outT) {
  __shared__ char ldsbuf[66560];  // K dbuf 2x16K @0 | V dbuf 2x16K @32768 | exch @65536

  int bh = blockIdx.x, tt = blockIdx.y;
  int tid = threadIdx.x;
  int w = tid >> 6, lane = tid & 63;
  int tw = w & 1, sw = w >> 1;
  int ln = lane & 31, h = lane >> 5;
  int t0 = tt * 64 + tw * 32;

  float* bmbuf = (float*)(ldsbuf + 65536);         // [tw*2+sw][32]
  float* lbuf  = (float*)(ldsbuf + 65536 + 512);   // [tw][32]

  auto stageK = [&](int buf, int sb, const char* kTb) {
#pragma unroll
    for (int it = 0; it < 4; ++it) {
      int bb = it * 4096 + tid * 16;
      int row = bb >> 8;
      int cb = (bb & 255) ^ ((row & 15) << 4);
      gl_lds16(kTb + (size_t)(sb * 64 + row) * 256 + cb, ldsbuf + buf * 16384 + bb);
    }
  };
  auto stageV = [&](int buf, int sb, const char* vb) {
#pragma unroll
    for (int it = 0; it < 4; ++it) {
      int bb = it * 4096 + tid * 16;
      int row = bb >> 7;
      int cb = (bb & 127) ^ ((row & 7) << 4);
      gl_lds16(vb + (size_t)row * 2048 + sb * 128 + cb, ldsbuf + 32768 + buf * 16384 + bb);
    }
  };

  short8 bq[8];
  f32x16 oacc[4];
  float m_r, l_r;
  int swz = (ln & 7) << 4;     // V-row & Q-tile swizzle
  int kswz = (ln & 15) << 4;   // K-row swizzle
  int krow = sw * 32 + ln;

  auto flash = [&](const char* kTb, const char* vb) {
    m_r = -1e30f; l_r = 0.f;
#pragma unroll
    for (int i = 0; i < 4; ++i)
#pragma unroll
      for (int r = 0; r < 16; ++r) oacc[i][r] = 0.f;

    stageK(0, 0, kTb); stageV(0, 0, vb);
    asm volatile("s_waitcnt vmcnt(0)" ::: "memory");
    BARRIER();

    for (int sb = 0; sb < 16; ++sb) {
      int cur = sb & 1;
      const char* K = ldsbuf + cur * 16384;
      const char* V = ldsbuf + 32768 + cur * 16384;
      f32x16 sa;
#pragma unroll
      for (int r = 0; r < 16; ++r) sa[r] = 0.f;

      // ---- P1: QK k=0..3 ----
      if (sb < 15) stageK(cur ^ 1, sb + 1, kTb);
      short8 ka0 = *(const short8*)(K + krow * 256 + ((0  + h * 16) ^ kswz));
      short8 ka1 = *(const short8*)(K + krow * 256 + ((32 + h * 16) ^ kswz));
      short8 ka2 = *(const short8*)(K + krow * 256 + ((64 + h * 16) ^ kswz));
      short8 ka3 = *(const short8*)(K + krow * 256 + ((96 + h * 16) ^ kswz));
      BARRIER();
      LGKM0();
      __builtin_amdgcn_s_setprio(1);
      sa = __builtin_amdgcn_mfma_f32_32x32x16_bf16(ka0, bq[0], sa, 0, 0, 0);
      sa = __builtin_amdgcn_mfma_f32_32x32x16_bf16(ka1, bq[1], sa, 0, 0, 0);
      sa = __builtin_amdgcn_mfma_f32_32x32x16_bf16(ka2, bq[2], sa, 0, 0, 0);
      sa = __builtin_amdgcn_mfma_f32_32x32x16_bf16(ka3, bq[3], sa, 0, 0, 0);
      __builtin_amdgcn_s_setprio(0);
      BARRIER();

      // ---- P2: QK k=4..7 ----
      if (sb < 15) stageV(cur ^ 1, sb + 1, vb);
      short8 kb0 = *(const short8*)(K + krow * 256 + ((128 + h * 16) ^ kswz));
      short8 kb1 = *(const short8*)(K + krow * 256 + ((160 + h * 16) ^ kswz));
      short8 kb2 = *(const short8*)(K + krow * 256 + ((192 + h * 16) ^ kswz));
      short8 kb3 = *(const short8*)(K + krow * 256 + ((224 + h * 16) ^ kswz));
      BARRIER();
      LGKM0();
      __builtin_amdgcn_s_setprio(1);
      sa = __builtin_amdgcn_mfma_f32_32x32x16_bf16(kb0, bq[4], sa, 0, 0, 0);
      sa = __builtin_amdgcn_mfma_f32_32x32x16_bf16(kb1, bq[5], sa, 0, 0, 0);
      sa = __builtin_amdgcn_mfma_f32_32x32x16_bf16(kb2, bq[6], sa, 0, 0, 0);
      sa = __builtin_amdgcn_mfma_f32_32x32x16_bf16(kb3, bq[7], sa, 0, 0, 0);
      __builtin_amdgcn_s_setprio(0);
      BARRIER();

      // ---- P3: joint softmax ----
      float bm = fmaxf(fmaxf(sa[0], sa[1]), fmaxf(sa[2], sa[3]));
      bm = fmaxf(bm, fmaxf(fmaxf(sa[4], sa[5]), fmaxf(sa[6], sa[7])));
      bm = fmaxf(bm, fmaxf(fmaxf(sa[8], sa[9]), fmaxf(sa[10], sa[11])));
      bm = fmaxf(bm, fmaxf(fmaxf(sa[12], sa[13]), fmaxf(sa[14], sa[15])));
      bm = fmaxf(bm, __shfl_xor(bm, 32));
      if (lane < 32) bmbuf[(tw * 2 + sw) * 32 + lane] = bm;
      LGKM0();
      BARRIER();
      bm = fmaxf(bm, bmbuf[(tw * 2 + (sw ^ 1)) * 32 + ln]);  // joint max over 64 s
      bool stay = __all(bm - m_r <= THR_RAW);
      if (!stay) {
        float mn = fmaxf(m_r, bm);
        float corr = exp2f_fast((m_r - mn) * CEXP);
        m_r = mn; l_r *= corr;
#pragma unroll
        for (int i = 0; i < 4; ++i)
#pragma unroll
          for (int r = 0; r < 16; ++r) oacc[i][r] *= corr;
      }
      float mnC = m_r * CEXP;
      float rs = 0.f;
#pragma unroll
      for (int r = 0; r < 16; ++r) {
        float p = exp2f_fast(__builtin_fmaf(sa[r], CEXP, -mnC));
        sa[r] = p; rs += p;
      }
      rs += __shfl_xor(rs, 32);
      l_r += rs;  // partial l over this wave's s-half

      short8 bp0, bp1;
      {
        u32 w0 = cvtpk(sa[0], sa[1]),  w1 = cvtpk(sa[2], sa[3]);
        u32 w2 = cvtpk(sa[4], sa[5]),  w3 = cvtpk(sa[6], sa[7]);
        swap32(w0, w2); swap32(w1, w3);
        bp0 = mk8(w0, w1, w2, w3);
        u32 w4 = cvtpk(sa[8], sa[9]),  w5 = cvtpk(sa[10], sa[11]);
        u32 w6 = cvtpk(sa[12], sa[13]), w7 = cvtpk(sa[14], sa[15]);
        swap32(w4, w6); swap32(w5, w7);
        bp1 = mk8(w4, w5, w6, w7);
      }

      // ---- P4: PV ks=0 ----
      int vc0 = sw * 64 + h * 16;
      short8 va0 = *(const short8*)(V + (0  + ln) * 128 + (vc0 ^ swz));
      short8 va1 = *(const short8*)(V + (32 + ln) * 128 + (vc0 ^ swz));
      short8 va2 = *(const short8*)(V + (64 + ln) * 128 + (vc0 ^ swz));
      short8 va3 = *(const short8*)(V + (96 + ln) * 128 + (vc0 ^ swz));
      BARRIER();
      LGKM0();
      __builtin_amdgcn_s_setprio(1);
      oacc[0] = __builtin_amdgcn_mfma_f32_32x32x16_bf16(va0, bp0, oacc[0], 0, 0, 0);
      oacc[1] = __builtin_amdgcn_mfma_f32_32x32x16_bf16(va1, bp0, oacc[1], 0, 0, 0);
      oacc[2] = __builtin_amdgcn_mfma_f32_32x32x16_bf16(va2, bp0, oacc[2], 0, 0, 0);
      oacc[3] = __builtin_amdgcn_mfma_f32_32x32x16_bf16(va3, bp0, oacc[3], 0, 0, 0);
      __builtin_amdgcn_s_setprio(0);
      BARRIER();

      // ---- P5: PV ks=1 ----
      int vc1 = sw * 64 + 32 + h * 16;
      short8 vb0 = *(const short8*)(V + (0  + ln) * 128 + (vc1 ^ swz));
      short8 vb1 = *(const short8*)(V + (32 + ln) * 128 + (vc1 ^ swz));
      short8 vb2 = *(const short8*)(V + (64 + ln) * 128 + (vc1 ^ swz));
      short8 vb3 = *(const short8*)(V + (96 + ln) * 128 + (vc1 ^ swz));
      BARRIER();
      LGKM0();
      __builtin_amdgcn_s_setprio(1);
      oacc[0] = __builtin_amdgcn_mfma_f32_32x32x16_bf16(vb0, bp1, oacc[0], 0, 0, 0);
      oacc[1] = __builtin_amdgcn_mfma_f32_32x32x16_bf16(vb1, bp1, oacc[1], 0, 0, 0);
      oacc[2] = __builtin_amdgcn_mfma_f32_32x32x16_bf16(vb2, bp1, oacc[2], 0, 0, 0);
      oacc[3] = __builtin_amdgcn_mfma_f32_32x32x16_bf16(vb3, bp1, oacc[3], 0, 0, 0);
      __builtin_amdgcn_s_setprio(0);
      asm volatile("s_waitcnt vmcnt(0)" ::: "memory");
      BARRIER();
    }
  };

  auto merge_sw = [&]() {  // O_total = O(sw0)+O(sw1); l_total; result lands in sw0
    float* mb = (float*)(ldsbuf + 32768 + tw * 16384);
    if (sw == 1) {
#pragma unroll
      for (int i = 0; i < 4; ++i)
#pragma unroll
        for (int r = 0; r < 16; ++r) mb[(i * 16 + r) * 64 + lane] = oacc[i][r];
      if (lane < 32) lbuf[tw * 32 + lane] = l_r;
    }
    LGKM0();
    BARRIER();
    if (sw == 0) {
#pragma unroll
      for (int i = 0; i < 4; ++i)
#pragma unroll
        for (int r = 0; r < 16; ++r) oacc[i][r] += mb[(i * 16 + r) * 64 + lane];
      l_r += lbuf[tw * 32 + ln];
    }
  };

  // ---------------- phase 1: _c tile = attn(e, c, c) ----------------
  const u16* qbase = eT + ((size_t)bh * LSEQ + t0 + ln) * CHD + h * 8;
#pragma unroll
  for (int k = 0; k < 8; ++k) bq[k] = *(const short8*)(qbase + k * 16);

  flash((const char*)(cT + (size_t)bh * LSEQ * CHD),
        (const char*)(cV + (size_t)bh * CHD * LSEQ));

  merge_sw();
  // sw0 writes normalized bf16 Q tile [32 t][256B c] (swizzled) for all waves
  if (sw == 0) {
    float inv = 1.0f / l_r;
    char* qt = ldsbuf + tw * 8192;
#pragma unroll
    for (int m = 0; m < 4; ++m)
#pragma unroll
      for (int q = 0; q < 8; ++q) {
        u32 pk = cvtpk(oacc[m][2 * q] * inv, oacc[m][2 * q + 1] * inv);
        int c2 = m * 64 + 4 * (q & 1) + 16 * (q >> 1) + 8 * h;
        *(u32*)(qt + ln * 256 + (c2 ^ swz)) = pk;
      }
  }
  LGKM0();
  BARRIER();
  {
    const char* qt = ldsbuf + tw * 8192;
#pragma unroll
    for (int k = 0; k < 8; ++k)
      bq[k] = *(const short8*)(qt + ln * 256 + ((k * 32 + h * 16) ^ swz));
  }
  LGKM0();
  BARRIER();  // all bq reads done before phase-2 staging overwrites K area

  // ---------------- phase 2: _e tile = attn(_c, e, e) ----------------
  flash((const char*)(eT + (size_t)bh * LSEQ * CHD),
        (const char*)(eV + (size_t)bh * CHD * LSEQ));

  merge_sw();
  BARRIER();
  if (sw == 0) {
    float inv = 1.0f / l_r;
    char* ot = ldsbuf + tw * 8192;
#pragma unroll
    for (int m = 0; m < 4; ++m)
#pragma unroll
      for (int q = 0; q < 8; ++q) {
        u32 pk = cvtpk(oacc[m][2 * q] * inv, oacc[m][2 * q + 1] * inv);
        int c2 = m * 64 + 4 * (q & 1) + 16 * (q >> 1) + 8 * h;
        *(u32*)(ot + ln * 256 + (c2 ^ swz)) = pk;
      }
    asm volatile("" ::: "memory");
    u16* orow = outT + ((size_t)bh * LSEQ + t0 + ln) * CHD;
#pragma unroll
    for (int it = 0; it < 8; ++it) {
      int col = h * 128 + it * 16;
      ushort8 d = *(const ushort8*)(ot + ln * 256 + (col ^ swz));
      *(ushort8*)((char*)orow + col) = d;
    }
  }
}

// ---- FUSED proj GEMM + BN stats + BN apply + swish (cooperative, 256 blocks = 1/CU) ----
// x never touches memory: GEMM acc stays in registers across two grid syncs.
__global__ __launch_bounds__(256) void k_projfused(const u16* __restrict__ Wm,
                                                   const u16* __restrict__ eT,
                                                   const float* __restrict__ bias,
                                                   float* __restrict__ pstat,   // [2][128][512] + scale/shift tail
                                                   const float* __restrict__ gamma,
                                                   const float* __restrict__ beta,
                                                   float* __restrict__ outp) {
  __shared__ char lds[65536];
  int lt = blockIdx.x, ot = blockIdx.y;
  int b = lt >> 3;
  int l0b = (lt & 7) * 128;
  int o0 = ot * 128;
  int tid = threadIdx.x, w = tid >> 6, lane = tid & 63, lo = lane & 15, hi = lane >> 4;
  int wm = w >> 1, wn = w & 1;
  const char* Wb = (const char*)Wm;
  const char* eTb = (const char*)eT;

  auto stageA = [&](int buf, int kb) {
    char* dst = lds + buf * 16384;
#pragma unroll
    for (int it = 0; it < 4; ++it) {
      int bb = it * 4096 + tid * 16;
      int row = bb >> 7;
      int cb = (bb & 127) ^ ((row & 7) << 4);
      gl_lds16(Wb + (size_t)(o0 + row) * 1024 + kb * 128 + cb, dst + bb);
    }
  };
  auto stageB = [&](int buf, int kb) {
    char* dst = lds + 32768 + buf * 16384;
    int page = b * 4 + (kb >> 1);
    int choff = (kb & 1) * 128;
#pragma unroll
    for (int it = 0; it < 4; ++it) {
      int bb = it * 4096 + tid * 16;
      int row = bb >> 7;
      int cb = (bb & 127) ^ ((row & 7) << 4);
      gl_lds16(eTb + ((size_t)page * 1024 + l0b + row) * 256 + choff + cb, dst + bb);
    }
  };

  floatx4 acc[4][4];
#pragma unroll
  for (int i = 0; i < 4; ++i)
#pragma unroll
    for (int j = 0; j < 4; ++j) { acc[i][j][0]=0.f; acc[i][j][1]=0.f; acc[i][j][2]=0.f; acc[i][j][3]=0.f; }

  stageA(0, 0); stageB(0, 0);

  for (int kb = 0; kb < 8; ++kb) {
    int cur = kb & 1;
    __builtin_amdgcn_s_barrier();
    if (kb < 7) { stageA(cur ^ 1, kb + 1); stageB(cur ^ 1, kb + 1); }
    if (kb < 7) { asm volatile("s_waitcnt vmcnt(8)" ::: "memory"); }
    else        { asm volatile("s_waitcnt vmcnt(0)" ::: "memory"); }
    __builtin_amdgcn_s_barrier();
    const char* A = lds + cur * 16384;
    const char* B = lds + 32768 + cur * 16384;
#pragma unroll
    for (int kk = 0; kk < 2; ++kk) {
      short8 af[4], bf[4];
#pragma unroll
      for (int mi = 0; mi < 4; ++mi) {
        int row = wm * 64 + mi * 16 + lo;
        af[mi] = *(const short8*)(A + row * 128 + ((kk * 64 + hi * 16) ^ ((row & 7) << 4)));
      }
#pragma unroll
      for (int ni = 0; ni < 4; ++ni) {
        int row = wn * 64 + ni * 16 + lo;
        bf[ni] = *(const short8*)(B + row * 128 + ((kk * 64 + hi * 16) ^ ((row & 7) << 4)));
      }
      __builtin_amdgcn_s_setprio(1);
#pragma unroll
      for (int mi = 0; mi < 4; ++mi)
#pragma unroll
        for (int ni = 0; ni < 4; ++ni)
          acc[mi][ni] = __builtin_amdgcn_mfma_f32_16x16x32_bf16(af[mi], bf[ni], acc[mi][ni], 0, 0, 0);
      __builtin_amdgcn_s_setprio(0);
    }
  }

  // epilogue A: add bias in-register; write non-atomic per-channel partials
  int prow = lt * 2 + wn;  // [0,128)
#pragma unroll
  for (int mi = 0; mi < 4; ++mi) {
#pragma unroll
    for (int r = 0; r < 4; ++r) {
      int o = o0 + wm * 64 + mi * 16 + hi * 4 + r;
      float bv = bias[o];
      float s = 0.f, q = 0.f;
#pragma unroll
      for (int ni = 0; ni < 4; ++ni) {
        float xv = acc[mi][ni][r] + bv;
        acc[mi][ni][r] = xv;  // keep live for apply phase
        s += xv; q += xv * xv;
      }
#pragma unroll
      for (int d = 1; d < 16; d <<= 1) { s += __shfl_xor(s, d); q += __shfl_xor(q, d); }
      if (lo == 0) {
        pstat[(size_t)prow * 512 + o] = s;
        pstat[65536 + (size_t)prow * 512 + o] = q;
      }
    }
  }

  __threadfence();
  cg::this_grid().sync();

  // epilogue B: each block reduces 2 channels -> scale/shift (stored in pstat tail)
  float* scale = pstat + 131072;
  float* shift = scale + 512;
  int bid = blockIdx.y * 64 + blockIdx.x;  // [0,256)
  if (tid < 128) {
    int chn = bid * 2 + (tid >> 6);
    int l = lane;  // 0..63 within each wave
    float s = pstat[(size_t)l * 512 + chn] + pstat[(size_t)(l + 64) * 512 + chn];
    float q = pstat[65536 + (size_t)l * 512 + chn] + pstat[65536 + (size_t)(l + 64) * 512 + chn];
#pragma unroll
    for (int d = 1; d < 64; d <<= 1) { s += __shfl_xor(s, d); q += __shfl_xor(q, d); }
    if (l == 0) {
      const float invn = 1.0f / 8192.0f;
      float mean = s * invn;
      float var = q * invn - mean * mean;
      float rstd = rsqrtf(var + 1e-5f);
      float g = gamma[chn] * rstd;
      scale[chn] = g;
      shift[chn] = beta[chn] - mean * g;
    }
  }

  __threadfence();
  cg::this_grid().sync();

  // epilogue C: apply BN+swish in-register, write final f32 output
#pragma unroll
  for (int mi = 0; mi < 4; ++mi) {
#pragma unroll
    for (int r = 0; r < 4; ++r) {
      int o = o0 + wm * 64 + mi * 16 + hi * 4 + r;
      float sc = scale[o], sh = shift[o];
#pragma unroll
      for (int ni = 0; ni < 4; ++ni) {
        float xn = acc[mi][ni][r] * sc + sh;
        float sg = 1.0f / (1.0f + __expf(-xn));
        outp[((size_t)b * 512 + o) * LSEQ + l0b + wn * 64 + ni * 16 + lo] = xn * sg;
      }
    }
  }
}

extern "C" void kernel_launch(void* const* d_in, const int* in_sizes, int n_in,
                              void* d_out, int out_size, void* d_ws, size_t ws_size,
                              hipStream_t stream) {
  const float* c     = (const float*)d_in[0];
  const float* e     = (const float*)d_in[1];
  const float* Wf    = (const float*)d_in[2];
  const float* bias  = (const float*)d_in[3];
  const float* gamma = (const float*)d_in[4];
  const float* beta  = (const float*)d_in[5];
  float* outp = (float*)d_out;

  char* ws = (char*)d_ws;
  const size_t TB = (size_t)32 * 1024 * 128 * 2;
  u16* eT  = (u16*)(ws);
  u16* cT  = (u16*)(ws + TB);
  u16* cV  = (u16*)(ws + 2 * TB);
  u16* eV  = (u16*)(ws + 3 * TB);
  u16* xT  = (u16*)(ws + 4 * TB);
  u16* Wbf = (u16*)(ws + 5 * TB);
  float* pstat = (float*)(ws + 5 * TB + (2 << 20));  // 2x128x512 f32 + scale/shift tail

  dim3 tb(256);

  k_prep<<<dim3(16, 4, 66), tb, 0, stream>>>(c, e, Wf, cV, cT, eV, eT, Wbf);
  k_attn<<<dim3(32, 16), tb, 0, stream>>>(eT, cT, cV, eV, xT);
  void* args[] = { (void*)&Wbf, (void*)&xT, (void*)&bias, (void*)&pstat,
                   (void*)&gamma, (void*)&beta, (void*)&outp };
  hipLaunchCooperativeKernel((const void*)k_projfused, dim3(64, 4), tb, args, 0, stream);
}

// Round 16
// 93.196 us; speedup vs baseline: 2.2015x; 2.2015x over previous
//
#include <hip/hip_runtime.h>
#include <hip/hip_bf16.h>

typedef __attribute__((ext_vector_type(8))) short short8;
typedef __attribute__((ext_vector_type(4))) float floatx4;
typedef __attribute__((ext_vector_type(4))) float f32x4;
typedef __attribute__((ext_vector_type(16))) float f32x16;
typedef unsigned short u16;
typedef unsigned int u32;
typedef __attribute__((ext_vector_type(4))) unsigned int u32x4;
typedef __attribute__((ext_vector_type(8))) unsigned short ushort8;

#define LSEQ 1024
#define CHD  128
#define CEXP 0.12751744900425577f   // (1/sqrt(128)) * log2(e)
#define THR_RAW 62.73318f           // 8 / CEXP

static __device__ __forceinline__ float b2f(u16 u) {
  union { u32 i; float f; } x; x.i = ((u32)u) << 16; return x.f;
}
static __device__ __forceinline__ u32 cvtpk(float a, float b) {
  u32 r;
  asm("v_cvt_pk_bf16_f32 %0, %1, %2" : "=v"(r) : "v"(a), "v"(b));
  return r;
}
static __device__ __forceinline__ void swap32(u32& a, u32& b) {
  asm("v_permlane32_swap_b32 %0, %1" : "+v"(a), "+v"(b));
}
static __device__ __forceinline__ short8 mk8(u32 a, u32 b, u32 c, u32 d) {
  union { u32x4 u; short8 s; } x;
  x.u[0] = a; x.u[1] = b; x.u[2] = c; x.u[3] = d;
  return x.s;
}
static __device__ __forceinline__ float exp2f_fast(float x) {
  float r;
  asm("v_exp_f32 %0, %1" : "=v"(r) : "v"(x));
  return r;
}
static __device__ __forceinline__ void gl_lds16(const void* g, void* l) {
  __builtin_amdgcn_global_load_lds((__attribute__((address_space(1))) const void*)g,
                                   (__attribute__((address_space(3))) void*)l, 16, 0, 0);
}
#define BARRIER() do { asm volatile("" ::: "memory"); __builtin_amdgcn_s_barrier(); asm volatile("" ::: "memory"); } while (0)
// write-drain only (cross-wave LDS handshakes); no sched_barrier -> compiler stays free
#define LGKMW()   do { asm volatile("s_waitcnt lgkmcnt(0)" ::: "memory"); } while (0)

// ---- prep both inputs (z<64) + W convert (z=64,65) ----
__global__ __launch_bounds__(256) void k_prep(const float* __restrict__ cin,
                                              const float* __restrict__ ein,
                                              const float* __restrict__ Wf,
                                              u16* __restrict__ cV, u16* __restrict__ cT,
                                              u16* __restrict__ eV, u16* __restrict__ eT,
                                              u16* __restrict__ wb) {
  __shared__ u16 tile[32][72];
  int z = blockIdx.z;
  int tid = threadIdx.x;
  if (z >= 64) {
    int wblk = (z - 64) * 64 + blockIdx.y * 16 + blockIdx.x;
    int base = (wblk * 256 + tid) * 8;
    f32x4 a = *(const f32x4*)(Wf + base);
    f32x4 b = *(const f32x4*)(Wf + base + 4);
    u32x4 u;
    u[0] = cvtpk(a[0], a[1]); u[1] = cvtpk(a[2], a[3]);
    u[2] = cvtpk(b[0], b[1]); u[3] = cvtpk(b[2], b[3]);
    *(u32x4*)(wb + base) = u;
    return;
  }
  const float* in = (z < 32) ? cin : ein;
  u16* outV = (z < 32) ? cV : eV;
  u16* outT = (z < 32) ? cT : eT;
  int bh = z & 31, c0 = blockIdx.y * 32, s0 = blockIdx.x * 64;
  int cl = tid >> 3, sc = tid & 7;
  size_t off = ((size_t)bh * CHD + c0 + cl) * LSEQ + s0 + sc * 8;
  f32x4 a = *(const f32x4*)(in + off);
  f32x4 b = *(const f32x4*)(in + off + 4);
  u32x4 u;
  u[0] = cvtpk(a[0], a[1]); u[1] = cvtpk(a[2], a[3]);
  u[2] = cvtpk(b[0], b[1]); u[3] = cvtpk(b[2], b[3]);
  *(u32x4*)(outV + off) = u;
  *(u32x4*)&tile[cl][sc * 8] = u;
  __syncthreads();
  int sl = tid >> 2, cc = tid & 3;
  ushort8 v;
#pragma unroll
  for (int j = 0; j < 8; ++j) v[j] = tile[cc * 8 + j][sl];
  *(ushort8*)(outT + ((size_t)bh * LSEQ + s0 + sl) * CHD + c0 + cc * 8) = v;
}

// ---- fused double flash attention: 4 waves (2 tw x 2 sw), phased schedule ----
// grid(32 bh, 16 tt), 256 thr. LDS 65.5KB -> 2 blocks/CU -> 2 waves/SIMD.
__global__ __launch_bounds__(256, 2) void k_attn(const u16* __restrict__ eT,
                                                 const u16* __restrict__ cT,
                                                 const u16* __restrict__ cV,
                                                 const u16* __restrict__ eV,
                                                 u16* __restrict__ outT) {
  __shared__ char ldsbuf[66560];  // K dbuf 2x16K @0 | V dbuf 2x16K @32768 | exch @65536

  int bh = blockIdx.x, tt = blockIdx.y;
  int tid = threadIdx.x;
  int w = tid >> 6, lane = tid & 63;
  int tw = w & 1, sw = w >> 1;
  int ln = lane & 31, h = lane >> 5;
  int t0 = tt * 64 + tw * 32;

  float* bmbuf = (float*)(ldsbuf + 65536);         // [tw*2+sw][32]
  float* lbuf  = (float*)(ldsbuf + 65536 + 512);   // [tw][32]

  auto stageK = [&](int buf, int sb, const char* kTb) {
#pragma unroll
    for (int it = 0; it < 4; ++it) {
      int bb = it * 4096 + tid * 16;
      int row = bb >> 8;
      int cb = (bb & 255) ^ ((row & 15) << 4);
      gl_lds16(kTb + (size_t)(sb * 64 + row) * 256 + cb, ldsbuf + buf * 16384 + bb);
    }
  };
  auto stageV = [&](int buf, int sb, const char* vb) {
#pragma unroll
    for (int it = 0; it < 4; ++it) {
      int bb = it * 4096 + tid * 16;
      int row = bb >> 7;
      int cb = (bb & 127) ^ ((row & 7) << 4);
      gl_lds16(vb + (size_t)row * 2048 + sb * 128 + cb, ldsbuf + 32768 + buf * 16384 + bb);
    }
  };

  short8 bq[8];
  f32x16 oacc[4];
  float m_r, l_r;
  int swz = (ln & 7) << 4;     // V-row & Q-tile swizzle
  int kswz = (ln & 15) << 4;   // K-row swizzle
  int krow = sw * 32 + ln;

  auto flash = [&](const char* kTb, const char* vb) {
    m_r = -1e30f; l_r = 0.f;
#pragma unroll
    for (int i = 0; i < 4; ++i)
#pragma unroll
      for (int r = 0; r < 16; ++r) oacc[i][r] = 0.f;

    stageK(0, 0, kTb); stageV(0, 0, vb);
    asm volatile("s_waitcnt vmcnt(0)" ::: "memory");
    BARRIER();

    for (int sb = 0; sb < 16; ++sb) {
      int cur = sb & 1;
      const char* K = ldsbuf + cur * 16384;
      const char* V = ldsbuf + 32768 + cur * 16384;
      f32x16 sa;
#pragma unroll
      for (int r = 0; r < 16; ++r) sa[r] = 0.f;

      // ---- P1: QK k=0..3 (loads scheduled freely; compiler emits partial lgkmcnt) ----
      if (sb < 15) stageK(cur ^ 1, sb + 1, kTb);
      short8 ka0 = *(const short8*)(K + krow * 256 + ((0  + h * 16) ^ kswz));
      short8 ka1 = *(const short8*)(K + krow * 256 + ((32 + h * 16) ^ kswz));
      short8 ka2 = *(const short8*)(K + krow * 256 + ((64 + h * 16) ^ kswz));
      short8 ka3 = *(const short8*)(K + krow * 256 + ((96 + h * 16) ^ kswz));
      BARRIER();
      __builtin_amdgcn_s_setprio(1);
      sa = __builtin_amdgcn_mfma_f32_32x32x16_bf16(ka0, bq[0], sa, 0, 0, 0);
      sa = __builtin_amdgcn_mfma_f32_32x32x16_bf16(ka1, bq[1], sa, 0, 0, 0);
      sa = __builtin_amdgcn_mfma_f32_32x32x16_bf16(ka2, bq[2], sa, 0, 0, 0);
      sa = __builtin_amdgcn_mfma_f32_32x32x16_bf16(ka3, bq[3], sa, 0, 0, 0);
      __builtin_amdgcn_s_setprio(0);
      BARRIER();

      // ---- P2: QK k=4..7 ----
      if (sb < 15) stageV(cur ^ 1, sb + 1, vb);
      short8 kb0 = *(const short8*)(K + krow * 256 + ((128 + h * 16) ^ kswz));
      short8 kb1 = *(const short8*)(K + krow * 256 + ((160 + h * 16) ^ kswz));
      short8 kb2 = *(const short8*)(K + krow * 256 + ((192 + h * 16) ^ kswz));
      short8 kb3 = *(const short8*)(K + krow * 256 + ((224 + h * 16) ^ kswz));
      BARRIER();
      __builtin_amdgcn_s_setprio(1);
      sa = __builtin_amdgcn_mfma_f32_32x32x16_bf16(kb0, bq[4], sa, 0, 0, 0);
      sa = __builtin_amdgcn_mfma_f32_32x32x16_bf16(kb1, bq[5], sa, 0, 0, 0);
      sa = __builtin_amdgcn_mfma_f32_32x32x16_bf16(kb2, bq[6], sa, 0, 0, 0);
      sa = __builtin_amdgcn_mfma_f32_32x32x16_bf16(kb3, bq[7], sa, 0, 0, 0);
      __builtin_amdgcn_s_setprio(0);
      BARRIER();

      // ---- P3: joint softmax ----
      float bm = fmaxf(fmaxf(sa[0], sa[1]), fmaxf(sa[2], sa[3]));
      bm = fmaxf(bm, fmaxf(fmaxf(sa[4], sa[5]), fmaxf(sa[6], sa[7])));
      bm = fmaxf(bm, fmaxf(fmaxf(sa[8], sa[9]), fmaxf(sa[10], sa[11])));
      bm = fmaxf(bm, fmaxf(fmaxf(sa[12], sa[13]), fmaxf(sa[14], sa[15])));
      bm = fmaxf(bm, __shfl_xor(bm, 32));
      if (lane < 32) bmbuf[(tw * 2 + sw) * 32 + lane] = bm;
      LGKMW();   // my bm write drained before partner reads
      BARRIER();
      bm = fmaxf(bm, bmbuf[(tw * 2 + (sw ^ 1)) * 32 + ln]);  // joint max over 64 s
      bool stay = __all(bm - m_r <= THR_RAW);
      if (!stay) {
        float mn = fmaxf(m_r, bm);
        float corr = exp2f_fast((m_r - mn) * CEXP);
        m_r = mn; l_r *= corr;
#pragma unroll
        for (int i = 0; i < 4; ++i)
#pragma unroll
          for (int r = 0; r < 16; ++r) oacc[i][r] *= corr;
      }
      float mnC = m_r * CEXP;
      float rs = 0.f;
#pragma unroll
      for (int r = 0; r < 16; ++r) {
        float p = exp2f_fast(__builtin_fmaf(sa[r], CEXP, -mnC));
        sa[r] = p; rs += p;
      }
      rs += __shfl_xor(rs, 32);
      l_r += rs;  // partial l over this wave's s-half

      short8 bp0, bp1;
      {
        u32 w0 = cvtpk(sa[0], sa[1]),  w1 = cvtpk(sa[2], sa[3]);
        u32 w2 = cvtpk(sa[4], sa[5]),  w3 = cvtpk(sa[6], sa[7]);
        swap32(w0, w2); swap32(w1, w3);
        bp0 = mk8(w0, w1, w2, w3);
        u32 w4 = cvtpk(sa[8], sa[9]),  w5 = cvtpk(sa[10], sa[11]);
        u32 w6 = cvtpk(sa[12], sa[13]), w7 = cvtpk(sa[14], sa[15]);
        swap32(w4, w6); swap32(w5, w7);
        bp1 = mk8(w4, w5, w6, w7);
      }

      // ---- P4: PV ks=0 ----
      int vc0 = sw * 64 + h * 16;
      short8 va0 = *(const short8*)(V + (0  + ln) * 128 + (vc0 ^ swz));
      short8 va1 = *(const short8*)(V + (32 + ln) * 128 + (vc0 ^ swz));
      short8 va2 = *(const short8*)(V + (64 + ln) * 128 + (vc0 ^ swz));
      short8 va3 = *(const short8*)(V + (96 + ln) * 128 + (vc0 ^ swz));
      BARRIER();
      __builtin_amdgcn_s_setprio(1);
      oacc[0] = __builtin_amdgcn_mfma_f32_32x32x16_bf16(va0, bp0, oacc[0], 0, 0, 0);
      oacc[1] = __builtin_amdgcn_mfma_f32_32x32x16_bf16(va1, bp0, oacc[1], 0, 0, 0);
      oacc[2] = __builtin_amdgcn_mfma_f32_32x32x16_bf16(va2, bp0, oacc[2], 0, 0, 0);
      oacc[3] = __builtin_amdgcn_mfma_f32_32x32x16_bf16(va3, bp0, oacc[3], 0, 0, 0);
      __builtin_amdgcn_s_setprio(0);
      BARRIER();

      // ---- P5: PV ks=1 ----
      int vc1 = sw * 64 + 32 + h * 16;
      short8 vb0 = *(const short8*)(V + (0  + ln) * 128 + (vc1 ^ swz));
      short8 vb1 = *(const short8*)(V + (32 + ln) * 128 + (vc1 ^ swz));
      short8 vb2 = *(const short8*)(V + (64 + ln) * 128 + (vc1 ^ swz));
      short8 vb3 = *(const short8*)(V + (96 + ln) * 128 + (vc1 ^ swz));
      BARRIER();
      __builtin_amdgcn_s_setprio(1);
      oacc[0] = __builtin_amdgcn_mfma_f32_32x32x16_bf16(vb0, bp1, oacc[0], 0, 0, 0);
      oacc[1] = __builtin_amdgcn_mfma_f32_32x32x16_bf16(vb1, bp1, oacc[1], 0, 0, 0);
      oacc[2] = __builtin_amdgcn_mfma_f32_32x32x16_bf16(vb2, bp1, oacc[2], 0, 0, 0);
      oacc[3] = __builtin_amdgcn_mfma_f32_32x32x16_bf16(vb3, bp1, oacc[3], 0, 0, 0);
      __builtin_amdgcn_s_setprio(0);
      asm volatile("s_waitcnt vmcnt(0)" ::: "memory");
      BARRIER();
    }
  };

  auto merge_sw = [&]() {  // O_total = O(sw0)+O(sw1); l_total; result lands in sw0
    float* mb = (float*)(ldsbuf + 32768 + tw * 16384);
    if (sw == 1) {
#pragma unroll
      for (int i = 0; i < 4; ++i)
#pragma unroll
        for (int r = 0; r < 16; ++r) mb[(i * 16 + r) * 64 + lane] = oacc[i][r];
      if (lane < 32) lbuf[tw * 32 + lane] = l_r;
    }
    LGKMW();
    BARRIER();
    if (sw == 0) {
#pragma unroll
      for (int i = 0; i < 4; ++i)
#pragma unroll
        for (int r = 0; r < 16; ++r) oacc[i][r] += mb[(i * 16 + r) * 64 + lane];
      l_r += lbuf[tw * 32 + ln];
    }
  };

  // ---------------- phase 1: _c tile = attn(e, c, c) ----------------
  const u16* qbase = eT + ((size_t)bh * LSEQ + t0 + ln) * CHD + h * 8;
#pragma unroll
  for (int k = 0; k < 8; ++k) bq[k] = *(const short8*)(qbase + k * 16);

  flash((const char*)(cT + (size_t)bh * LSEQ * CHD),
        (const char*)(cV + (size_t)bh * CHD * LSEQ));

  merge_sw();
  // sw0 writes normalized bf16 Q tile [32 t][256B c] (swizzled) for all waves
  if (sw == 0) {
    float inv = 1.0f / l_r;
    char* qt = ldsbuf + tw * 8192;
#pragma unroll
    for (int m = 0; m < 4; ++m)
#pragma unroll
      for (int q = 0; q < 8; ++q) {
        u32 pk = cvtpk(oacc[m][2 * q] * inv, oacc[m][2 * q + 1] * inv);
        int c2 = m * 64 + 4 * (q & 1) + 16 * (q >> 1) + 8 * h;
        *(u32*)(qt + ln * 256 + (c2 ^ swz)) = pk;
      }
  }
  LGKMW();
  BARRIER();
  {
    const char* qt = ldsbuf + tw * 8192;
#pragma unroll
    for (int k = 0; k < 8; ++k)
      bq[k] = *(const short8*)(qt + ln * 256 + ((k * 32 + h * 16) ^ swz));
  }
  LGKMW();
  BARRIER();  // all bq reads done before phase-2 staging overwrites K area

  // ---------------- phase 2: _e tile = attn(_c, e, e) ----------------
  flash((const char*)(eT + (size_t)bh * LSEQ * CHD),
        (const char*)(eV + (size_t)bh * CHD * LSEQ));

  merge_sw();
  BARRIER();
  if (sw == 0) {
    float inv = 1.0f / l_r;
    char* ot = ldsbuf + tw * 8192;
#pragma unroll
    for (int m = 0; m < 4; ++m)
#pragma unroll
      for (int q = 0; q < 8; ++q) {
        u32 pk = cvtpk(oacc[m][2 * q] * inv, oacc[m][2 * q + 1] * inv);
        int c2 = m * 64 + 4 * (q & 1) + 16 * (q >> 1) + 8 * h;
        *(u32*)(ot + ln * 256 + (c2 ^ swz)) = pk;
      }
    asm volatile("" ::: "memory");
    u16* orow = outT + ((size_t)bh * LSEQ + t0 + ln) * CHD;
#pragma unroll
    for (int it = 0; it < 8; ++it) {
      int col = h * 128 + it * 16;
      ushort8 d = *(const ushort8*)(ot + ln * 256 + (col ^ swz));
      *(ushort8*)((char*)orow + col) = d;
    }
  }
}

// ---- proj GEMM 512(o) x 8192(b*l) x 512(c): 128x128 tile, BK=64 ----
// Stats: non-atomic per-(block,wn) partials to pstat.
__global__ __launch_bounds__(256) void k_proj(const u16* __restrict__ Wm,
                                              const u16* __restrict__ eT,
                                              const float* __restrict__ bias,
                                              u16* __restrict__ x,
                                              float* __restrict__ pstat) {  // [2][128][512]
  __shared__ char lds[65536];
  int lt = blockIdx.x, ot = blockIdx.y;
  int b = lt >> 3;
  int l0b = (lt & 7) * 128;
  int o0 = ot * 128;
  int tid = threadIdx.x, w = tid >> 6, lane = tid & 63, lo = lane & 15, hi = lane >> 4;
  int wm = w >> 1, wn = w & 1;
  const char* Wb = (const char*)Wm;
  const char* eTb = (const char*)eT;

  auto stageA = [&](int buf, int kb) {
    char* dst = lds + buf * 16384;
#pragma unroll
    for (int it = 0; it < 4; ++it) {
      int bb = it * 4096 + tid * 16;
      int row = bb >> 7;
      int cb = (bb & 127) ^ ((row & 7) << 4);
      gl_lds16(Wb + (size_t)(o0 + row) * 1024 + kb * 128 + cb, dst + bb);
    }
  };
  auto stageB = [&](int buf, int kb) {
    char* dst = lds + 32768 + buf * 16384;
    int page = b * 4 + (kb >> 1);
    int choff = (kb & 1) * 128;
#pragma unroll
    for (int it = 0; it < 4; ++it) {
      int bb = it * 4096 + tid * 16;
      int row = bb >> 7;
      int cb = (bb & 127) ^ ((row & 7) << 4);
      gl_lds16(eTb + ((size_t)page * 1024 + l0b + row) * 256 + choff + cb, dst + bb);
    }
  };

  floatx4 acc[4][4];
#pragma unroll
  for (int i = 0; i < 4; ++i)
#pragma unroll
    for (int j = 0; j < 4; ++j) { acc[i][j][0]=0.f; acc[i][j][1]=0.f; acc[i][j][2]=0.f; acc[i][j][3]=0.f; }

  stageA(0, 0); stageB(0, 0);

  for (int kb = 0; kb < 8; ++kb) {
    int cur = kb & 1;
    __builtin_amdgcn_s_barrier();
    if (kb < 7) { stageA(cur ^ 1, kb + 1); stageB(cur ^ 1, kb + 1); }
    if (kb < 7) { asm volatile("s_waitcnt vmcnt(8)" ::: "memory"); }
    else        { asm volatile("s_waitcnt vmcnt(0)" ::: "memory"); }
    __builtin_amdgcn_s_barrier();
    const char* A = lds + cur * 16384;
    const char* B = lds + 32768 + cur * 16384;
#pragma unroll
    for (int kk = 0; kk < 2; ++kk) {
      short8 af[4], bf[4];
#pragma unroll
      for (int mi = 0; mi < 4; ++mi) {
        int row = wm * 64 + mi * 16 + lo;
        af[mi] = *(const short8*)(A + row * 128 + ((kk * 64 + hi * 16) ^ ((row & 7) << 4)));
      }
#pragma unroll
      for (int ni = 0; ni < 4; ++ni) {
        int row = wn * 64 + ni * 16 + lo;
        bf[ni] = *(const short8*)(B + row * 128 + ((kk * 64 + hi * 16) ^ ((row & 7) << 4)));
      }
      __builtin_amdgcn_s_setprio(1);
#pragma unroll
      for (int mi = 0; mi < 4; ++mi)
#pragma unroll
        for (int ni = 0; ni < 4; ++ni)
          acc[mi][ni] = __builtin_amdgcn_mfma_f32_16x16x32_bf16(af[mi], bf[ni], acc[mi][ni], 0, 0, 0);
      __builtin_amdgcn_s_setprio(0);
    }
  }

  // epilogue: bias + x write (bf16) + per-channel partials (non-atomic, unique rows)
  int prow = lt * 2 + wn;  // [0,128)
#pragma unroll
  for (int mi = 0; mi < 4; ++mi) {
#pragma unroll
    for (int r = 0; r < 4; ++r) {
      int o = o0 + wm * 64 + mi * 16 + hi * 4 + r;
      float bv = bias[o];
      float s = 0.f, q = 0.f;
#pragma unroll
      for (int ni = 0; ni < 4; ++ni) {
        float xv = acc[mi][ni][r] + bv;
        x[((size_t)b * 512 + o) * LSEQ + l0b + wn * 64 + ni * 16 + lo] = cvtpk(xv, xv) & 0xffff;
        s += xv; q += xv * xv;
      }
#pragma unroll
      for (int d = 1; d < 16; d <<= 1) { s += __shfl_xor(s, d); q += __shfl_xor(q, d); }
      if (lo == 0) {
        pstat[(size_t)prow * 512 + o] = s;
        pstat[65536 + (size_t)prow * 512 + o] = q;
      }
    }
  }
}

// ---- BN stats (per-block redundant reduce of its 2 channels) + apply + swish ----
__global__ __launch_bounds__(256) void k_final(const u16* __restrict__ x,
                                               const float* __restrict__ pstat,
                                               const float* __restrict__ gamma,
                                               const float* __restrict__ beta,
                                               float* __restrict__ out) {
  __shared__ float sscale[2], sshift[2];
  int bid = blockIdx.x;
  int tid = threadIdx.x;
  if (tid < 128) {
    int k = tid >> 6;
    int chn = (bid * 2 + k) & 511;
    int l = tid & 63;
    float s = pstat[(size_t)l * 512 + chn] + pstat[(size_t)(l + 64) * 512 + chn];
    float q = pstat[65536 + (size_t)l * 512 + chn] + pstat[65536 + (size_t)(l + 64) * 512 + chn];
#pragma unroll
    for (int d = 1; d < 64; d <<= 1) { s += __shfl_xor(s, d); q += __shfl_xor(q, d); }
    if (l == 0) {
      const float invn = 1.0f / 8192.0f;
      float mean = s * invn;
      float var = q * invn - mean * mean;
      float rstd = rsqrtf(var + 1e-5f);
      float g = gamma[chn] * rstd;
      sscale[k] = g;
      sshift[k] = beta[chn] - mean * g;
    }
  }
  __syncthreads();
  int base = (bid * 256 + tid) * 8;
  int k2 = tid >> 7;
  float sc = sscale[k2], sh = sshift[k2];
  ushort8 vx = *(const ushort8*)(x + base);
  f32x4 o0, o1;
#pragma unroll
  for (int j = 0; j < 8; ++j) {
    float xn = b2f(vx[j]) * sc + sh;
    float sg = 1.0f / (1.0f + __expf(-xn));
    float r = xn * sg;
    if (j < 4) o0[j] = r; else o1[j - 4] = r;
  }
  *(f32x4*)(out + base) = o0;
  *(f32x4*)(out + base + 4) = o1;
}

extern "C" void kernel_launch(void* const* d_in, const int* in_sizes, int n_in,
                              void* d_out, int out_size, void* d_ws, size_t ws_size,
                              hipStream_t stream) {
  const float* c     = (const float*)d_in[0];
  const float* e     = (const float*)d_in[1];
  const float* Wf    = (const float*)d_in[2];
  const float* bias  = (const float*)d_in[3];
  const float* gamma = (const float*)d_in[4];
  const float* beta  = (const float*)d_in[5];
  float* outp = (float*)d_out;

  char* ws = (char*)d_ws;
  const size_t TB = (size_t)32 * 1024 * 128 * 2;
  u16* eT  = (u16*)(ws);
  u16* cT  = (u16*)(ws + TB);
  u16* cV  = (u16*)(ws + 2 * TB);
  u16* eV  = (u16*)(ws + 3 * TB);
  u16* xT  = (u16*)(ws + 4 * TB);
  u16* Wbf = (u16*)(ws + 5 * TB);
  float* pstat = (float*)(ws + 5 * TB + (2 << 20));  // 2 x 128 x 512 f32
  u16* x   = (u16*)(ws + 6 * TB);

  dim3 tb(256);

  k_prep<<<dim3(16, 4, 66), tb, 0, stream>>>(c, e, Wf, cV, cT, eV, eT, Wbf);
  k_attn<<<dim3(32, 16), tb, 0, stream>>>(eT, cT, cV, eV, xT);
  k_proj<<<dim3(64, 4), tb, 0, stream>>>(Wbf, xT, bias, x, pstat);
  k_final<<<dim3(2048), tb, 0, stream>>>(x, pstat, gamma, beta, outp);
}